// Round 9
// baseline (806.308 us; speedup 1.0000x reference)
//
#include <hip/hip_runtime.h>

#define N_NODES 100000
#define N_EDGES 3200000
#define DIM 256

typedef _Float16 half_t;
typedef __attribute__((ext_vector_type(4))) _Float16 half4;
typedef __attribute__((ext_vector_type(8))) _Float16 half8;
typedef __attribute__((ext_vector_type(4))) float floatx4;

// ---------------------------------------------------------------------------
// Geometry: buckets of 128 rows (row >> 7). 782 buckets.
// ---------------------------------------------------------------------------
#define BM 128
#define BK 32
#define LDK 40

#define NBUCK 782                        // ceil(100000 / 128)
#define RPB 128
#define CAPG 4608                        // LDS ledge cap (mean 4096 + 8 sigma)
#define EPB 8192                         // edges per hist/scatter block
#define NEB 391                          // ceil(3.2M / 8192)

// ---------------------------------------------------------------------------
// W cast+transpose: wT[n][k] = (f16) w[k][n].
// ---------------------------------------------------------------------------
__global__ __launch_bounds__(256) void castw_kernel(const float* __restrict__ w,
                                                    half_t* __restrict__ wT) {
    __shared__ float tile[32][33];
    int bk = blockIdx.x * 32;
    int bn = blockIdx.y * 32;
    int tx = threadIdx.x & 31, ty = threadIdx.x >> 5;
#pragma unroll
    for (int i = 0; i < 4; i++)
        tile[ty + i * 8][tx] = w[(size_t)(bk + ty + i * 8) * DIM + bn + tx];
    __syncthreads();
#pragma unroll
    for (int i = 0; i < 4; i++)
        wT[(size_t)(bn + ty + i * 8) * DIM + bk + tx] = (half_t)tile[tx][ty + i * 8];
}

// ---------------------------------------------------------------------------
// MFMA GEMM: support[M,256] (f16) = x[M,256] (fp32) @ wT^T.  (round-3 proven)
// ---------------------------------------------------------------------------
__global__ __launch_bounds__(512) void gemm_f16_kernel(const float* __restrict__ A,
                                                       const half_t* __restrict__ BT,
                                                       half_t* __restrict__ C, int M) {
    __shared__ half_t As[BM][LDK];
    __shared__ half_t Bs[256][LDK];

    const int tid = threadIdx.x;
    const int wid = tid >> 6, lane = tid & 63;
    const int wm = wid & 1, wn = wid >> 1;   // 2 x 4
    const int row0 = blockIdx.x * BM;
    const int lr = lane & 15;
    const int quad = lane >> 4;

    floatx4 acc[4][4] = {};

    const int ar = tid >> 2;
    const int ac = (tid & 3) * 8;
    const bool avalid = (row0 + ar) < M;
    const float* aptr = A + (size_t)(row0 + ar) * DIM + ac;

    for (int k0 = 0; k0 < DIM; k0 += BK) {
        {
            const float4* src = (const float4*)(aptr + k0);
            half_t* dst = &As[ar][ac];
#pragma unroll
            for (int i = 0; i < 2; i++) {
                float4 v = avalid ? src[i] : make_float4(0.f, 0.f, 0.f, 0.f);
                half4 h;
                h.x = (half_t)v.x; h.y = (half_t)v.y;
                h.z = (half_t)v.z; h.w = (half_t)v.w;
                ((half4*)dst)[i] = h;
            }
        }
        {
#pragma unroll
            for (int i = 0; i < 2; i++) {
                int ch = tid + i * 512;
                int r = ch >> 2, cb = (ch & 3) * 8;
                half8 v = *(const half8*)(BT + (size_t)r * DIM + k0 + cb);
                *(half8*)&Bs[r][cb] = v;
            }
        }
        __syncthreads();

        half8 a[4], b[4];
#pragma unroll
        for (int i = 0; i < 4; i++)
            a[i] = *(const half8*)&As[wm * 64 + i * 16 + lr][quad * 8];
#pragma unroll
        for (int j = 0; j < 4; j++)
            b[j] = *(const half8*)&Bs[wn * 64 + j * 16 + lr][quad * 8];
#pragma unroll
        for (int i = 0; i < 4; i++)
#pragma unroll
            for (int j = 0; j < 4; j++)
                acc[i][j] = __builtin_amdgcn_mfma_f32_16x16x32_f16(a[i], b[j], acc[i][j], 0, 0, 0);
        __syncthreads();
    }

#pragma unroll
    for (int i = 0; i < 4; i++) {
#pragma unroll
        for (int j = 0; j < 4; j++) {
            int gc = wn * 64 + j * 16 + lr;
            int grb = row0 + wm * 64 + i * 16 + quad * 4;
#pragma unroll
            for (int r = 0; r < 4; r++) {
                int gr = grb + r;
                if (gr < M) C[(size_t)gr * DIM + gc] = (half_t)acc[i][j][r];
            }
        }
    }
}

// ---------------------------------------------------------------------------
// Pass 1: exact bucket histogram (LDS-aggregated).
// ---------------------------------------------------------------------------
__global__ __launch_bounds__(512) void hist_kernel(const int* __restrict__ erow,
                                                   int* __restrict__ bcnt) {
    __shared__ int lh[NBUCK];
    for (int b = threadIdx.x; b < NBUCK; b += 512) lh[b] = 0;
    __syncthreads();
    int base4 = blockIdx.x * (EPB / 4);
#pragma unroll
    for (int i = 0; i < 4; i++) {
        int idx4 = base4 + i * 512 + threadIdx.x;
        if (idx4 < N_EDGES / 4) {
            int4 r4 = ((const int4*)erow)[idx4];
            atomicAdd(&lh[r4.x >> 7], 1);
            atomicAdd(&lh[r4.y >> 7], 1);
            atomicAdd(&lh[r4.z >> 7], 1);
            atomicAdd(&lh[r4.w >> 7], 1);
        }
    }
    __syncthreads();
    for (int b = threadIdx.x; b < NBUCK; b += 512)
        if (lh[b]) atomicAdd(&bcnt[b * 16], lh[b]);   // stride-16 counters
}

// ---------------------------------------------------------------------------
// Pass 1b: exclusive scan of 782 counts (1 block, 512 thr x 2 slots) ->
// dense bases bbase[] and cursor re-init.
// ---------------------------------------------------------------------------
__global__ __launch_bounds__(512) void scan_buckets_kernel(int* __restrict__ bcnt,
                                                           int* __restrict__ bbase) {
    __shared__ int s[1024];
    int t = threadIdx.x;
    int v0 = (t < NBUCK) ? bcnt[t * 16] : 0;
    int v1 = (t + 512 < NBUCK) ? bcnt[(t + 512) * 16] : 0;
    s[t] = v0; s[t + 512] = v1;
    __syncthreads();
    for (int off = 1; off < 1024; off <<= 1) {
        int a = (t >= off) ? s[t - off] : 0;
        int b = (t + 512 >= off) ? s[t + 512 - off] : 0;
        __syncthreads();
        s[t] += a; s[t + 512] += b;
        __syncthreads();
    }
    if (t < NBUCK) {
        int ex = s[t] - v0;
        bbase[t] = ex;
        bcnt[t * 16] = ex;   // cursor for scatter chunk reservation
    }
    if (t + 512 < NBUCK) {
        int ex = s[t + 512] - v1;
        bbase[t + 512] = ex;
        bcnt[(t + 512) * 16] = ex;
    }
    if (t == 0) bbase[NBUCK] = N_EDGES;
}

// ---------------------------------------------------------------------------
// Pass 2: LDS-staged counting sort per block -> run-coalesced writes into
// DENSE bucket-major tmp (workspace).  Replaces per-edge divergent 8B stores
// with per-run copies (~10-edge runs, consecutive lanes -> coalesced).
// record: .x = (rowlocal << 17) | col  (rowlocal < 128, col < 2^17)
// ---------------------------------------------------------------------------
__global__ __launch_bounds__(512, 4) void scatter_kernel(const int* __restrict__ erow,
                                                         const int* __restrict__ ecol,
                                                         const float* __restrict__ eval,
                                                         int* __restrict__ gcur,
                                                         int2* __restrict__ tmp) {
    __shared__ int lh[NBUCK];        // hist -> rank cursor
    __shared__ int lstart[NBUCK + 1];
    __shared__ int gbase[NBUCK];
    __shared__ int ssum[1024];
    __shared__ __align__(16) int2 stage[EPB];   // 64 KB

    const int t = threadIdx.x;
    for (int b = t; b < NBUCK; b += 512) lh[b] = 0;
    __syncthreads();

    int base4 = blockIdx.x * (EPB / 4);
    // phase 1: local histogram
#pragma unroll
    for (int i = 0; i < 4; i++) {
        int idx4 = base4 + i * 512 + t;
        if (idx4 < N_EDGES / 4) {
            int4 r4 = ((const int4*)erow)[idx4];
            atomicAdd(&lh[r4.x >> 7], 1);
            atomicAdd(&lh[r4.y >> 7], 1);
            atomicAdd(&lh[r4.z >> 7], 1);
            atomicAdd(&lh[r4.w >> 7], 1);
        }
    }
    __syncthreads();
    // local scan (1024-wide Hillis, 2 slots/thread) + global chunk reservation
    int v0 = (t < NBUCK) ? lh[t] : 0;
    int v1 = (t + 512 < NBUCK) ? lh[t + 512] : 0;
    ssum[t] = v0; ssum[t + 512] = v1;
    __syncthreads();
    for (int off = 1; off < 1024; off <<= 1) {
        int a = (t >= off) ? ssum[t - off] : 0;
        int b = (t + 512 >= off) ? ssum[t + 512 - off] : 0;
        __syncthreads();
        ssum[t] += a; ssum[t + 512] += b;
        __syncthreads();
    }
    if (t < NBUCK) {
        int ex = ssum[t] - v0;
        lstart[t] = ex;
        gbase[t] = v0 ? atomicAdd(&gcur[t * 16], v0) : 0;
        lh[t] = ex;   // rank cursor
    }
    if (t + 512 < NBUCK) {
        int ex = ssum[t + 512] - v1;
        lstart[t + 512] = ex;
        gbase[t + 512] = v1 ? atomicAdd(&gcur[(t + 512) * 16], v1) : 0;
        lh[t + 512] = ex;
    }
    if (t == NBUCK - 512) lstart[NBUCK] = ssum[NBUCK - 1];
    __syncthreads();

    // phase 2: re-read (L2-hot) & rank into LDS staging
#define SCAT(R, C, V)                                                      \
    {                                                                      \
        int _r = (R), _c = (C);                                            \
        int _b = _r >> 7;                                                  \
        int _rank = atomicAdd(&lh[_b], 1);                                 \
        stage[_rank] = make_int2(((_r & 127) << 17) | _c, __float_as_int(V)); \
    }
#pragma unroll
    for (int i = 0; i < 4; i++) {
        int idx4 = base4 + i * 512 + t;
        if (idx4 < N_EDGES / 4) {
            int4 r4 = ((const int4*)erow)[idx4];
            int4 c4 = ((const int4*)ecol)[idx4];
            float4 v4 = ((const float4*)eval)[idx4];
            SCAT(r4.x, c4.x, v4.x);
            SCAT(r4.y, c4.y, v4.y);
            SCAT(r4.z, c4.z, v4.z);
            SCAT(r4.w, c4.w, v4.w);
        }
    }
#undef SCAT
    __syncthreads();

    // phase 3: run-coalesced copy to dense tmp (wave w -> buckets w, w+8, ...)
    const int wid = t >> 6, lane = t & 63;
    for (int b = wid; b < NBUCK; b += 8) {
        int ls = lstart[b];
        int n = lstart[b + 1] - ls;
        int gb = gbase[b];
        for (int c = lane; c < n; c += 64)
            tmp[(size_t)gb + c] = stage[ls + c];
    }
}

// ---------------------------------------------------------------------------
// Pass 3 (fused): one block per bucket (782 x 512 thr, 38.4 KB LDS ->
// 4 blocks/CU = 32 waves/CU).  Phase A: LDS CSR build over 128 local rows.
// Phase B: round-3 gather loop (half-wave per edge, full D), edges from LDS.
// ---------------------------------------------------------------------------
__global__ __launch_bounds__(512, 8) void csr_spmm_kernel(
        const half_t* __restrict__ support, const int* __restrict__ bbase,
        const int2* __restrict__ tmp, float* __restrict__ out) {
    __shared__ int lh[RPB];
    __shared__ int s[RPB];
    __shared__ int roff[RPB + 1];
    __shared__ __align__(16) int2 ledge[CAPG];

    const int b = blockIdx.x;
    const int t = threadIdx.x;
    const int beg = bbase[b];
    int cnt = bbase[b + 1] - beg;
    if (cnt > CAPG) cnt = CAPG;
    const int2* src = tmp + beg;
    const int row0 = b * RPB;

    // ---- Phase A: LDS CSR build ----
    if (t < RPB) lh[t] = 0;
    __syncthreads();
    for (int e = t; e < cnt; e += 512)
        atomicAdd(&lh[src[e].x >> 17], 1);
    __syncthreads();

    if (t < RPB) s[t] = lh[t];
    __syncthreads();
    for (int off = 1; off < RPB; off <<= 1) {
        int u = 0;
        if (t < RPB && t >= off) u = s[t - off];
        __syncthreads();
        if (t < RPB) s[t] += u;
        __syncthreads();
    }
    if (t < RPB) {
        int ex = s[t] - lh[t];
        roff[t] = ex;
        lh[t] = ex;   // rank cursor
    }
    if (t == 0) roff[RPB] = cnt;
    __syncthreads();

    for (int e = t; e < cnt; e += 512) {
        int2 q = src[e];
        int lr = q.x >> 17;
        int rank = atomicAdd(&lh[lr], 1);
        ledge[rank] = make_int2(q.x & 0x1FFFF, q.y);
    }
    __syncthreads();

    // ---- Phase B: gather spmm (full D), 8 waves x 16 rows ----
    const int wid = t >> 6, lane = t & 63;
    const int h = lane >> 5;
    const int j = lane & 31;

    for (int r = wid; r < RPB; r += 8) {
        int row = row0 + r;
        if (row >= N_NODES) continue;           // wave-uniform
        int e = roff[r];
        int end = roff[r + 1];

        float acc[8] = {0.f, 0.f, 0.f, 0.f, 0.f, 0.f, 0.f, 0.f};

        if ((e & 1) && e < end) {               // parity peel (16B-align LDS int4)
            int2 q = ledge[e];
            half8 sv = *(const half8*)(support + (size_t)q.x * DIM + j * 8);
            float v = (h == 0) ? __int_as_float(q.y) : 0.f;
#pragma unroll
            for (int d = 0; d < 8; d++) acc[d] += v * (float)sv[d];
            e++;
        }

        for (; e + 15 < end; e += 16) {
            int4 pa = *(const int4*)&ledge[e + 2 * h];
            int4 pb = *(const int4*)&ledge[e + 4 + 2 * h];
            int4 pc = *(const int4*)&ledge[e + 8 + 2 * h];
            int4 pd = *(const int4*)&ledge[e + 12 + 2 * h];
            half8 s0 = *(const half8*)(support + (size_t)pa.x * DIM + j * 8);
            half8 s1 = *(const half8*)(support + (size_t)pa.z * DIM + j * 8);
            half8 s2 = *(const half8*)(support + (size_t)pb.x * DIM + j * 8);
            half8 s3 = *(const half8*)(support + (size_t)pb.z * DIM + j * 8);
            half8 s4 = *(const half8*)(support + (size_t)pc.x * DIM + j * 8);
            half8 s5 = *(const half8*)(support + (size_t)pc.z * DIM + j * 8);
            half8 s6 = *(const half8*)(support + (size_t)pd.x * DIM + j * 8);
            half8 s7 = *(const half8*)(support + (size_t)pd.z * DIM + j * 8);
            float v0 = __int_as_float(pa.y), v1 = __int_as_float(pa.w);
            float v2 = __int_as_float(pb.y), v3 = __int_as_float(pb.w);
            float v4 = __int_as_float(pc.y), v5 = __int_as_float(pc.w);
            float v6 = __int_as_float(pd.y), v7 = __int_as_float(pd.w);
#pragma unroll
            for (int d = 0; d < 8; d++)
                acc[d] += v0 * (float)s0[d] + v1 * (float)s1[d]
                        + v2 * (float)s2[d] + v3 * (float)s3[d]
                        + v4 * (float)s4[d] + v5 * (float)s5[d]
                        + v6 * (float)s6[d] + v7 * (float)s7[d];
        }
        for (; e + 1 < end; e += 2) {
            int2 q = ledge[e + h];
            half8 sv = *(const half8*)(support + (size_t)q.x * DIM + j * 8);
            float v = __int_as_float(q.y);
#pragma unroll
            for (int d = 0; d < 8; d++) acc[d] += v * (float)sv[d];
        }
        if (e < end) {
            int2 q = ledge[e];
            half8 sv = *(const half8*)(support + (size_t)q.x * DIM + j * 8);
            float v = (h == 0) ? __int_as_float(q.y) : 0.f;
#pragma unroll
            for (int d = 0; d < 8; d++) acc[d] += v * (float)sv[d];
        }

        float r0, r1, r2, r3, g0, g1, g2, g3;
        if (h == 0) {
            r0 = acc[0]; r1 = acc[1]; r2 = acc[2]; r3 = acc[3];
            g0 = acc[4]; g1 = acc[5]; g2 = acc[6]; g3 = acc[7];
        } else {
            r0 = acc[4]; r1 = acc[5]; r2 = acc[6]; r3 = acc[7];
            g0 = acc[0]; g1 = acc[1]; g2 = acc[2]; g3 = acc[3];
        }
        r0 += __shfl_xor(g0, 32, 64);
        r1 += __shfl_xor(g1, 32, 64);
        r2 += __shfl_xor(g2, 32, 64);
        r3 += __shfl_xor(g3, 32, 64);

        *(float4*)(out + (size_t)row * DIM + j * 8 + h * 4) =
            make_float4(r0, r1, r2, r3);
    }
}

extern "C" void kernel_launch(void* const* d_in, const int* in_sizes, int n_in,
                              void* d_out, int out_size, void* d_ws, size_t ws_size,
                              hipStream_t stream) {
    const float* x    = (const float*)d_in[0];
    const float* w    = (const float*)d_in[1];
    const int*   erow = (const int*)d_in[2];
    const int*   ecol = (const int*)d_in[3];
    const float* eval = (const float*)d_in[4];
    float* out = (float*)d_out;

    // workspace: support 51.2MB | wT 128KB | bcnt 50KB | bbase 3.2KB | tmp 25.6MB
    char* ws = (char*)d_ws;
    half_t* support = (half_t*)ws;                  // 51,200,000 B
    half_t* wT      = (half_t*)(ws + 51200000);     //    131,072 B
    int*    bcnt    = (int*)(ws + 51331072);        // 782*64 B stride-16 cursors
    int*    bbase   = (int*)(ws + 51381120);        // 783*4 B
    int2*   tmp     = (int2*)(ws + 51384256);       // 25,600,000 B (dense, ends 76.98MB)

    hipMemsetAsync(bcnt, 0, NBUCK * 16 * sizeof(int), stream);

    castw_kernel<<<dim3(8, 8), 256, 0, stream>>>(w, wT);

    dim3 ggrid((N_NODES + BM - 1) / BM, 1);
    gemm_f16_kernel<<<ggrid, 512, 0, stream>>>(x, wT, support, N_NODES);

    hist_kernel<<<NEB, 512, 0, stream>>>(erow, bcnt);
    scan_buckets_kernel<<<1, 512, 0, stream>>>(bcnt, bbase);
    scatter_kernel<<<NEB, 512, 0, stream>>>(erow, ecol, eval, bcnt, tmp);
    csr_spmm_kernel<<<NBUCK, 512, 0, stream>>>(support, bbase, tmp, out);
}